// Round 13
// baseline (308.609 us; speedup 1.0000x reference)
//
#include <hip/hip_runtime.h>
#include <hip/hip_bf16.h>

#define Bq 4
#define Sq 2048
#define Dq 1024
#define Hq 16
#define HDq 64
#define MR (Bq*Sq)   // 8192 rows

typedef __attribute__((ext_vector_type(8))) short bf16x8;
typedef __attribute__((ext_vector_type(4))) float f32x4;
typedef __attribute__((ext_vector_type(16))) float f32x16;

__device__ __forceinline__ unsigned short f2bf(float f){
  unsigned int x = __builtin_bit_cast(unsigned int, f);
  x += 0x7fffu + ((x >> 16) & 1u);          // round-to-nearest-even
  return (unsigned short)(x >> 16);
}

// HW packed f32x2 -> bf16x2 (RTNE)
__device__ __forceinline__ unsigned cvtpk(float a, float b){
  unsigned r;
  asm("v_cvt_pk_bf16_f32 %0, %1, %2" : "=v"(r) : "v"(a), "v"(b));
  return r;
}

#define MFMA(a,b,c)   __builtin_amdgcn_mfma_f32_16x16x32_bf16((a),(b),(c),0,0,0)
#define MFMA32(a,b,c) __builtin_amdgcn_mfma_f32_32x32x16_bf16((a),(b),(c),0,0,0)

#define SC_Q 0.18033688f   // 0.125 * log2(e), folded into q projection

// async global->LDS, 16B per lane; LDS dest = wave-uniform base + lane*16
__device__ __forceinline__ void gload16(const unsigned short* g, unsigned short* l){
  __builtin_amdgcn_global_load_lds(
      (const __attribute__((address_space(1))) void*)g,
      (__attribute__((address_space(3))) void*)l, 16, 0, 0);
}

// ---------------------------------------------------------------------------
// Pass -1: X fp32 -> bf16 (Q,K,V via blockIdx.y)
// ---------------------------------------------------------------------------
__global__ __launch_bounds__(256) void cvt_bf16x3(
    const float* __restrict__ X0, const float* __restrict__ X1, const float* __restrict__ X2,
    unsigned short* __restrict__ O0, unsigned short* __restrict__ O1, unsigned short* __restrict__ O2)
{
  const int z = blockIdx.y;
  const float* X = z==0?X0 : z==1?X1 : X2;
  unsigned short* O = z==0?O0 : z==1?O1 : O2;
  const size_t i = ((size_t)blockIdx.x*256 + threadIdx.x)*8;
  const float4 a = *(const float4*)(X+i);
  const float4 b = *(const float4*)(X+i+4);
  union { unsigned u[4]; int4 v; } pk;
  pk.u[0] = cvtpk(a.x, a.y);
  pk.u[1] = cvtpk(a.z, a.w);
  pk.u[2] = cvtpk(b.x, b.y);
  pk.u[3] = cvtpk(b.z, b.w);
  *(int4*)(O+i) = pk.v;
}

// ---------------------------------------------------------------------------
// Pass 0: W [k][n] fp32  ->  Wt [n][k] bf16   (4 weights via blockIdx.z)
// ---------------------------------------------------------------------------
__global__ __launch_bounds__(256) void transpose_w(
    const float* __restrict__ W0, const float* __restrict__ W1,
    const float* __restrict__ W2, const float* __restrict__ W3,
    unsigned short* __restrict__ T0, unsigned short* __restrict__ T1,
    unsigned short* __restrict__ T2, unsigned short* __restrict__ T3)
{
  __shared__ float tile[32][33];
  const int z = blockIdx.z;
  const float* W = z==0?W0 : z==1?W1 : z==2?W2 : W3;
  unsigned short* T = z==0?T0 : z==1?T1 : z==2?T2 : T3;
  const int k0 = blockIdx.x*32, n0 = blockIdx.y*32;
  const int tx = threadIdx.x & 31, ty = threadIdx.x >> 5;   // 32 x 8
  #pragma unroll
  for (int i=0;i<4;i++) tile[ty+i*8][tx] = W[(size_t)(k0+ty+i*8)*Dq + n0+tx];
  __syncthreads();
  #pragma unroll
  for (int i=0;i<4;i++) T[(size_t)(n0+ty+i*8)*Dq + k0+tx] = f2bf(tile[tx][ty+i*8]);
}

// ---------------------------------------------------------------------------
// Pass 0b: V [b][s][h*64+d] bf16 -> V^T [bh][d][s] bf16 (once)
// ---------------------------------------------------------------------------
__global__ __launch_bounds__(256) void transpose_v(
    const unsigned short* __restrict__ Vb, unsigned short* __restrict__ Vo)
{
  __shared__ unsigned short t2[64][72];      // [d][s], pad 72
  const int bh = blockIdx.y;                 // 64 = b*16+h
  const int b = bh >> 4, h = bh & 15;
  const int s0 = blockIdx.x * 64;
  const int tid = threadIdx.x;
  const int r = tid >> 3, c8 = tid & 7;      // 32 rows x 8 chunks
  #pragma unroll
  for (int i=0;i<2;i++){
    int s = r + i*32;
    union { int4 v; unsigned short u[8]; } uu;
    uu.v = *(const int4*)(Vb + ((size_t)b*Sq + s0 + s)*Dq + h*HDq + c8*8);
    #pragma unroll
    for (int jj=0;jj<8;jj++){
      int j = (jj + c8) & 7;                 // rotate -> 2 lanes/bank (free)
      t2[c8*8 + j][s] = uu.u[j];
    }
  }
  __syncthreads();
  #pragma unroll
  for (int i=0;i<2;i++){
    int d = r + i*32;
    *(int4*)(Vo + ((size_t)bh*HDq + d)*Sq + s0 + c8*8) = *(const int4*)&t2[d][c8*8];
  }
}

// ---------------------------------------------------------------------------
// GEMM mainloop (R10 config — best measured): 128x128 tile, BK=32, 3 LDS
// buffers (48KB), stage tile t+2 while computing t, s_waitcnt vmcnt(4),
// ONE barrier per K-step. Swizzle chunk' = chunk ^ ((row>>1)&3) (conflict-free,
// verified: SQ_LDS_BANK_CONFLICT = 0).
// ---------------------------------------------------------------------------
__device__ __forceinline__ void gemm_loop(const unsigned short* __restrict__ A,
    const unsigned short* __restrict__ Bt,
    int bm, int bn, unsigned short* Al, unsigned short* Bl, f32x4 acc[4][4])
{
  const int tid = threadIdx.x;
  const int lane = tid & 63, wid = tid >> 6;
  const int lr = lane & 15, lg = lane >> 4;
  const int wm = wid >> 1, wn = wid & 1;

  #define STG(buf, k0) { \
    unsigned short* Ad = Al + (buf)*4096 + wid*512; \
    unsigned short* Bd = Bl + (buf)*4096 + wid*512; \
    _Pragma("unroll") \
    for (int i=0;i<2;i++){ \
      const int row = i*64 + (tid>>2); \
      const int cl  = (tid&3) ^ ((row>>1)&3); \
      gload16(A  + (size_t)(bm*128+row)*Dq + (k0) + cl*8, Ad + i*2048); \
      gload16(Bt + (size_t)(bn*128+row)*Dq + (k0) + cl*8, Bd + i*2048); \
    } }

  STG(0, 0);
  STG(1, 32);
  asm volatile("s_waitcnt vmcnt(4)" ::: "memory");   // tile 0 landed
  __syncthreads();

  const int cr = (lg ^ ((lr >> 1) & 3)) * 8;         // swizzled read chunk
  for (int t = 0; t < 32; ++t){
    const int buf = t % 3;
    const unsigned short* Ab = Al + buf*4096;
    const unsigned short* Bb = Bl + buf*4096;
    bf16x8 af[4], bfv[4];
    #pragma unroll
    for (int mt=0;mt<4;mt++) af[mt]  = *(const bf16x8*)(Ab + (wm*64+mt*16+lr)*32 + cr);
    #pragma unroll
    for (int nt=0;nt<4;nt++) bfv[nt] = *(const bf16x8*)(Bb + (wn*64+nt*16+lr)*32 + cr);

    if (t + 2 < 32) {
      STG((t+2)%3, (t+2)*32);                        // buf was last read at t-1
      asm volatile("s_waitcnt vmcnt(4)" ::: "memory"); // tile t+1 landed
    } else if (t == 30) {
      asm volatile("s_waitcnt vmcnt(0)" ::: "memory"); // tail: tile 31 landed
    }

    #pragma unroll
    for (int mt=0;mt<4;mt++)
      #pragma unroll
      for (int nt=0;nt<4;nt++)
        acc[mt][nt] = MFMA(af[mt], bfv[nt], acc[mt][nt]);

    __syncthreads();                                 // readers of buf done
  }
  #undef STG
}

// ---------------------------------------------------------------------------
// Pass 1: q/k/v = bf16( (Xbf @ W + b + lev) * scl )
// ---------------------------------------------------------------------------
__global__ __launch_bounds__(256, 3) void proj_gemm(
    const unsigned short* __restrict__ Aq, const unsigned short* __restrict__ Ak, const unsigned short* __restrict__ Av,
    const float* __restrict__ Lq, const float* __restrict__ Lk, const float* __restrict__ Lv,
    const unsigned short* __restrict__ Tq, const unsigned short* __restrict__ Tk, const unsigned short* __restrict__ Tv,
    const float* __restrict__ bqp, const float* __restrict__ bkp, const float* __restrict__ bvp,
    unsigned short* __restrict__ Oq, unsigned short* __restrict__ Ok, unsigned short* __restrict__ Ov)
{
  __shared__ __align__(16) unsigned short Al[3*4096];
  __shared__ __align__(16) unsigned short Bl[3*4096];

  const int bid = blockIdx.x;                     // 0..1535, 1536 % 8 == 0
  const int swz = (bid & 7)*192 + (bid >> 3);     // XCD-contiguous, bijective
  const int z   = swz >> 9;
  const int rem = swz & 511;
  const int bm  = rem >> 3, bn = rem & 7;

  const unsigned short* A = z==0?Aq : z==1?Ak : Av;
  const float* Lev = z==0?Lq : z==1?Lk : Lv;
  const unsigned short* Bt = z==0?Tq : z==1?Tk : Tv;
  const float* bias = z==0?bqp : z==1?bkp : bvp;
  unsigned short* Out = z==0?Oq : z==1?Ok : Ov;
  const float scl = (z==0) ? SC_Q : 1.0f;

  f32x4 acc[4][4];
  #pragma unroll
  for (int mt=0;mt<4;mt++)
    #pragma unroll
    for (int nt=0;nt<4;nt++) acc[mt][nt] = (f32x4){0.f,0.f,0.f,0.f};

  gemm_loop(A, Bt, bm, bn, Al, Bl, acc);

  const int tid = threadIdx.x, lane = tid&63, wid = tid>>6;
  const int lr = lane&15, lg = lane>>4, wm = wid>>1, wn = wid&1;
  const int colb = bn*128 + wn*64;
  float bcol[4];
  #pragma unroll
  for (int nt=0;nt<4;nt++) bcol[nt] = bias[colb + nt*16 + lr];
  #pragma unroll
  for (int mt=0;mt<4;mt++){
    int g = bm*128 + wm*64 + mt*16 + lg*4;
    #pragma unroll
    for (int r=0;r<4;r++){
      size_t ro = (size_t)(g+r)*Dq;
      #pragma unroll
      for (int nt=0;nt<4;nt++){
        int col = colb + nt*16 + lr;
        float v = (acc[mt][nt][r] + bcol[nt] + Lev[ro + col]) * scl;
        Out[ro + col] = f2bf(v);
      }
    }
  }
}

// ---------------------------------------------------------------------------
// Pass 2: flash attention, swapped-QK^T 32x32, QK-one-tile-ahead pipeline:
// per iter: [sync][prefetch][QK-low(t+1)][softmax(t)][pack+PV(t)][QK-high(t+1)]
// [stage K(t+2),V(t+1)]. QK(t+1) MFMAs are register-independent of softmax(t)
// -> MFMA pipe runs under the VALU phase within each wave. QK-high placed
// after PV to cap live S-state (VGPR < 128 cliff).
// ---------------------------------------------------------------------------
__device__ __forceinline__ float comb_max(float x){ return fmaxf(x, __shfl_xor(x, 32, 64)); }
__device__ __forceinline__ float comb_sum(float x){ return x + __shfl_xor(x, 32, 64); }
__device__ __forceinline__ float max3(float a, float b, float c){ return fmaxf(fmaxf(a,b),c); }

// pack 16 f32 P-values into two PV A-frags; 4 shfl (pre-selected payload):
// partner needs: from hi=0 lanes their w2,w3,w6,w7; from hi=1 their w0,w1,w4,w5.
__device__ __forceinline__ void pack_p(const f32x16& t, int hi, bf16x8& c0, bf16x8& c1){
  unsigned w[8];
  #pragma unroll
  for (int j=0;j<8;j++) w[j] = cvtpk(t[2*j], t[2*j+1]);
  unsigned z0 = hi ? w[0] : w[2];
  unsigned z1 = hi ? w[1] : w[3];
  unsigned z2 = hi ? w[4] : w[6];
  unsigned z3 = hi ? w[5] : w[7];
  unsigned x0 = (unsigned)__shfl_xor((int)z0, 32, 64);
  unsigned x1 = (unsigned)__shfl_xor((int)z1, 32, 64);
  unsigned x2 = (unsigned)__shfl_xor((int)z2, 32, 64);
  unsigned x3 = (unsigned)__shfl_xor((int)z3, 32, 64);
  union { unsigned u[4]; bf16x8 v; } p0, p1;
  p0.u[0] = hi ? x0   : w[0];
  p0.u[1] = hi ? x1   : w[1];
  p0.u[2] = hi ? w[2] : x0;
  p0.u[3] = hi ? w[3] : x1;
  p1.u[0] = hi ? x2   : w[4];
  p1.u[1] = hi ? x3   : w[5];
  p1.u[2] = hi ? w[6] : x2;
  p1.u[3] = hi ? w[7] : x3;
  c0 = p0.v; c1 = p1.v;
}

__global__ __launch_bounds__(512, 4) void attn_k(
    const unsigned short* qb, const unsigned short* __restrict__ kb,
    const unsigned short* __restrict__ vt, unsigned short* cb)
{
  __shared__ unsigned short Kl[2][64*64];   // [key][d-chunk swizzled]
  __shared__ unsigned short Vl[2][64*64];   // [d][key-chunk swizzled]
  __shared__ float Rl[8][32];               // per-wave q-indexed broadcast

  const int bid = blockIdx.x;
  const int swz = (bid & 7)*64 + (bid >> 3);     // 512 % 8 == 0: bijective
  const int qt = swz & 7, bh = swz >> 3;         // 8 q-tiles x 64 heads
  const int b = bh >> 4, h = bh & 15;
  const size_t base = (size_t)b*Sq*Dq + (size_t)h*HDq;

  const int tid = threadIdx.x, lane = tid & 63, wid = tid >> 6;  // 8 waves
  const int ln31 = lane & 31, hi = lane >> 5;
  const int q0 = qt*256 + wid*32;

  bf16x8 qf[4];
  {
    const unsigned short* qp = qb + base + (size_t)(q0 + ln31)*Dq + hi*8;
    #pragma unroll
    for (int dk=0;dk<4;dk++) qf[dk] = *(const bf16x8*)(qp + dk*16);
  }

  const int kRow = tid >> 3, kCh = tid & 7;
  const unsigned short* kSrc = kb + base + (size_t)kRow*Dq + kCh*8;
  const unsigned short* vSrc = vt + ((size_t)bh*HDq + kRow)*Sq + kCh*8;
  const int wOff = kRow*64 + ((kCh ^ (kRow & 7))*8);

  // ---- prologue: stage K(0), V(0), K(1) ----
  {
    int4 k0r = *(const int4*)kSrc;
    int4 v0r = *(const int4*)vSrc;
    int4 k1r = *(const int4*)(kSrc + (size_t)64*Dq);
    *(int4*)&Kl[0][wOff] = k0r;
    *(int4*)&Vl[0][wOff] = v0r;
    *(int4*)&Kl[1][wOff] = k1r;
  }

  f32x16 o0 = (f32x16)(0.0f), o1 = (f32x16)(0.0f);
  float m = -1e30f, l = 0.f;

  __syncthreads();                               // prologue staging visible

  // ---- S(0) from Kl[0] ----
  f32x16 c0 = (f32x16)(0.0f), c1 = (f32x16)(0.0f);
  #pragma unroll
  for (int dk=0;dk<4;dk++){
    const int c = hi + dk*2;
    bf16x8 kf0 = *(const bf16x8*)&Kl[0][(ln31)*64    + ((c ^ (ln31 & 7))*8)];
    bf16x8 kf1 = *(const bf16x8*)&Kl[0][(32+ln31)*64 + ((c ^ (ln31 & 7))*8)];
    c0 = MFMA32(kf0, qf[dk], c0);
    c1 = MFMA32(kf1, qf[dk], c1);
  }

  int4 kreg = {0,0,0,0}, vreg = {0,0,0,0};

  for (int kt = 0; kt < Sq/64; ++kt){
    __syncthreads();                             // prev iter's staging visible;
                                                 // all waves past their reads
    const int pn = (kt+1) & 1;                   // K(t+1) buffer
    if (kt+2 < Sq/64) kreg = *(const int4*)(kSrc + (size_t)(kt+2)*64*Dq);
    if (kt+1 < Sq/64) vreg = *(const int4*)(vSrc + (kt+1)*64);

    // ---- QK-low(t+1): keys 0..31 of next tile (overlaps softmax below) ----
    f32x16 n0 = (f32x16)(0.0f);
    if (kt+1 < Sq/64){
      #pragma unroll
      for (int dk=0;dk<4;dk++){
        const int c = hi + dk*2;
        bf16x8 kf0 = *(const bf16x8*)&Kl[pn][(ln31)*64 + ((c ^ (ln31 & 7))*8)];
        n0 = MFMA32(kf0, qf[dk], n0);
      }
    }

    // ---- softmax on c0,c1 (S(t)) ----
    float u0 = max3(max3(c0[0], c0[1],  c0[2]),  max3(c0[3],  c0[4],  c0[5]),
                    max3(c0[6], c0[7],  c0[8]));
    float u1 = max3(max3(c0[9], c0[10], c0[11]), max3(c0[12], c0[13], c0[14]),
                    c0[15]);
    float u2 = max3(max3(c1[0], c1[1],  c1[2]),  max3(c1[3],  c1[4],  c1[5]),
                    max3(c1[6], c1[7],  c1[8]));
    float u3 = max3(max3(c1[9], c1[10], c1[11]), max3(c1[12], c1[13], c1[14]),
                    c1[15]);
    float tmax = comb_max(max3(max3(u0, u1, u2), u3, -1e30f));

    if (__any(tmax > m + 8.0f)){
      float mn = fmaxf(m, tmax);
      float al = __builtin_amdgcn_exp2f(m - mn);
      m = mn;
      l *= al;
      if (hi == 0) Rl[wid][ln31] = al;
      asm volatile("" ::: "memory");
      f32x4 av[4];
      #pragma unroll
      for (int g=0; g<4; g++) av[g] = *(const f32x4*)&Rl[wid][g*8 + hi*4];
      #pragma unroll
      for (int r=0;r<16;r++){ o0[r] *= av[r>>2][r&3]; o1[r] *= av[r>>2][r&3]; }
    }

    float s0 = 0.f, s1 = 0.f, s2 = 0.f, s3 = 0.f;
    #pragma unroll
    for (int r=0;r<16;r+=4){
      float a0 = __builtin_amdgcn_exp2f(c0[r]   - m); c0[r]   = a0; s0 += a0;
      float a1 = __builtin_amdgcn_exp2f(c0[r+1] - m); c0[r+1] = a1; s1 += a1;
      float a2 = __builtin_amdgcn_exp2f(c0[r+2] - m); c0[r+2] = a2; s2 += a2;
      float a3 = __builtin_amdgcn_exp2f(c0[r+3] - m); c0[r+3] = a3; s3 += a3;
    }
    #pragma unroll
    for (int r=0;r<16;r+=4){
      float a0 = __builtin_amdgcn_exp2f(c1[r]   - m); c1[r]   = a0; s0 += a0;
      float a1 = __builtin_amdgcn_exp2f(c1[r+1] - m); c1[r+1] = a1; s1 += a1;
      float a2 = __builtin_amdgcn_exp2f(c1[r+2] - m); c1[r+2] = a2; s2 += a2;
      float a3 = __builtin_amdgcn_exp2f(c1[r+3] - m); c1[r+3] = a3; s3 += a3;
    }
    l += comb_sum((s0 + s1) + (s2 + s3));

    // ---- pack + PV(t) from Vl[t&1] ----
    {
      const int p = kt & 1;
      bf16x8 pa0, pa1, pa2, pa3;
      pack_p(c0, hi, pa0, pa1);
      pack_p(c1, hi, pa2, pa3);
      #pragma unroll
      for (int c=0;c<4;c++){
        bf16x8 pa = c==0?pa0 : c==1?pa1 : c==2?pa2 : pa3;
        const int vc = 2*c + hi;
        bf16x8 vf0 = *(const bf16x8*)&Vl[p][(ln31)*64    + ((vc ^ (ln31 & 7))*8)];
        bf16x8 vf1 = *(const bf16x8*)&Vl[p][(32+ln31)*64 + ((vc ^ (ln31 & 7))*8)];
        o0 = MFMA32(pa, vf0, o0);
        o1 = MFMA32(pa, vf1, o1);
      }
    }

    // ---- QK-high(t+1): keys 32..63 of next tile ----
    f32x16 n1 = (f32x16)(0.0f);
    if (kt+1 < Sq/64){
      #pragma unroll
      for (int dk=0;dk<4;dk++){
        const int c = hi + dk*2;
        bf16x8 kf1 = *(const bf16x8*)&Kl[pn][(32+ln31)*64 + ((c ^ (ln31 & 7))*8)];
        n1 = MFMA32(kf1, qf[dk], n1);
      }
    }

    // ---- stage K(t+2) -> Kl[t&1], V(t+1) -> Vl[(t+1)&1] ----
    // Safe pre-barrier: no concurrent reader touches these bufs this iter
    // (QK reads Kl[(t+1)&1], PV reads Vl[t&1]).
    if (kt+2 < Sq/64) *(int4*)&Kl[kt & 1][wOff] = kreg;
    if (kt+1 < Sq/64) *(int4*)&Vl[pn][wOff]     = vreg;

    c0 = n0; c1 = n1;
  }

  // ---- epilogue: O / l, write ctx ----
  float linv = __builtin_amdgcn_rcpf(l);
  if (hi == 0) Rl[wid][ln31] = linv;
  asm volatile("" ::: "memory");
  f32x4 lv[4];
  #pragma unroll
  for (int g=0; g<4; g++) lv[g] = *(const f32x4*)&Rl[wid][g*8 + hi*4];
  #pragma unroll
  for (int r=0;r<16;r++){
    int q = (r&3) + 8*(r>>2) + 4*hi;
    size_t ro = base + (size_t)(q0 + q)*Dq;
    cb[ro + ln31]      = f2bf(o0[r] * lv[r>>2][r&3]);
    cb[ro + 32 + ln31] = f2bf(o1[r] * lv[r>>2][r&3]);
  }
}

// ---------------------------------------------------------------------------
// Pass 3: out = ctx @ Wo + bo   (fp32 out); 1D grid 512 + XCD swizzle
// ---------------------------------------------------------------------------
__global__ __launch_bounds__(256, 3) void out_gemm(
    const unsigned short* __restrict__ Ctx, const unsigned short* __restrict__ To,
    const float* __restrict__ bop, float* __restrict__ Out)
{
  __shared__ __align__(16) unsigned short Al[3*4096];
  __shared__ __align__(16) unsigned short Bl[3*4096];

  const int bid = blockIdx.x;                    // 0..511
  const int swz = (bid & 7)*64 + (bid >> 3);     // XCD-contiguous, bijective
  const int bm  = swz >> 3, bn = swz & 7;

  f32x4 acc[4][4];
  #pragma unroll
  for (int mt=0;mt<4;mt++)
    #pragma unroll
    for (int nt=0;nt<4;nt++) acc[mt][nt] = (f32x4){0.f,0.f,0.f,0.f};

  gemm_loop(Ctx, To, bm, bn, Al, Bl, acc);

  const int tid = threadIdx.x, lane = tid&63, wid = tid>>6;
  const int lr = lane&15, lg = lane>>4, wm = wid>>1, wn = wid&1;
  const int colb = bn*128 + wn*64;
  float bcol[4];
  #pragma unroll
  for (int nt=0;nt<4;nt++) bcol[nt] = bop[colb + nt*16 + lr];
  #pragma unroll
  for (int mt=0;mt<4;mt++){
    int g = bm*128 + wm*64 + mt*16 + lg*4;
    #pragma unroll
    for (int r=0;r<4;r++){
      size_t ro = (size_t)(g+r)*Dq;
      #pragma unroll
      for (int nt=0;nt<4;nt++){
        int col = colb + nt*16 + lr;
        Out[ro + col] = acc[mt][nt][r] + bcol[nt];
      }
    }
  }
}

// ---------------------------------------------------------------------------
extern "C" void kernel_launch(void* const* d_in, const int* in_sizes, int n_in,
                              void* d_out, int out_size, void* d_ws, size_t ws_size,
                              hipStream_t stream) {
  const float* Q    = (const float*)d_in[0];
  const float* Qlev = (const float*)d_in[1];
  const float* K    = (const float*)d_in[2];
  const float* Klev = (const float*)d_in[3];
  const float* V    = (const float*)d_in[4];
  const float* Vlev = (const float*)d_in[5];
  const float* Wq   = (const float*)d_in[6];
  const float* bq   = (const float*)d_in[7];
  const float* Wk   = (const float*)d_in[8];
  const float* bk   = (const float*)d_in[9];
  const float* Wv   = (const float*)d_in[10];
  const float* bv   = (const float*)d_in[11];
  const float* Wo   = (const float*)d_in[12];
  const float* bo   = (const float*)d_in[13];

  unsigned short* qbuf = (unsigned short*)d_ws;
  unsigned short* kbuf = qbuf + (size_t)MR*Dq;
  unsigned short* vbuf = kbuf + (size_t)MR*Dq;
  unsigned short* xq   = vbuf + (size_t)MR*Dq;   // bf16(Q); later aliased as V^T
  unsigned short* xk   = xq   + (size_t)MR*Dq;
  unsigned short* xv   = xk   + (size_t)MR*Dq;
  unsigned short* Tq   = xv   + (size_t)MR*Dq;
  unsigned short* Tk   = Tq + (size_t)Dq*Dq;
  unsigned short* Tv   = Tk + (size_t)Dq*Dq;
  unsigned short* To   = Tv + (size_t)Dq*Dq;
  unsigned short* vtb  = xq;                     // alias: xq dead after proj_gemm

  cvt_bf16x3<<<dim3(MR*Dq/(256*8), 3), 256, 0, stream>>>(Q, K, V, xq, xk, xv);
  transpose_w<<<dim3(Dq/32, Dq/32, 4), 256, 0, stream>>>(Wq,Wk,Wv,Wo, Tq,Tk,Tv,To);
  proj_gemm<<<dim3(1536), 256, 0, stream>>>(
      xq,xk,xv, Qlev,Klev,Vlev, Tq,Tk,Tv, bq,bk,bv, qbuf,kbuf,vbuf);
  transpose_v<<<dim3(Sq/64, Bq*Hq), 256, 0, stream>>>(vbuf, vtb);
  attn_k<<<dim3(512), 512, 0, stream>>>(qbuf, kbuf, vtb, qbuf);
  out_gemm<<<dim3(512), 256, 0, stream>>>(qbuf, To, bo, (float*)d_out);
}

// Round 14
// 251.653 us; speedup vs baseline: 1.2263x; 1.2263x over previous
//
#include <hip/hip_runtime.h>
#include <hip/hip_bf16.h>

#define Bq 4
#define Sq 2048
#define Dq 1024
#define Hq 16
#define HDq 64
#define MR (Bq*Sq)   // 8192 rows

typedef __attribute__((ext_vector_type(8))) short bf16x8;
typedef __attribute__((ext_vector_type(4))) float f32x4;
typedef __attribute__((ext_vector_type(16))) float f32x16;

__device__ __forceinline__ unsigned short f2bf(float f){
  unsigned int x = __builtin_bit_cast(unsigned int, f);
  x += 0x7fffu + ((x >> 16) & 1u);          // round-to-nearest-even
  return (unsigned short)(x >> 16);
}

// HW packed f32x2 -> bf16x2 (RTNE)
__device__ __forceinline__ unsigned cvtpk(float a, float b){
  unsigned r;
  asm("v_cvt_pk_bf16_f32 %0, %1, %2" : "=v"(r) : "v"(a), "v"(b));
  return r;
}

#define MFMA(a,b,c)   __builtin_amdgcn_mfma_f32_16x16x32_bf16((a),(b),(c),0,0,0)
#define MFMA32(a,b,c) __builtin_amdgcn_mfma_f32_32x32x16_bf16((a),(b),(c),0,0,0)

#define SC_Q 0.18033688f   // 0.125 * log2(e), folded into q projection

// async global->LDS, 16B per lane; LDS dest = wave-uniform base + lane*16
__device__ __forceinline__ void gload16(const unsigned short* g, unsigned short* l){
  __builtin_amdgcn_global_load_lds(
      (const __attribute__((address_space(1))) void*)g,
      (__attribute__((address_space(3))) void*)l, 16, 0, 0);
}

// ---------------------------------------------------------------------------
// Pass -1: X fp32 -> bf16 (Q,K,V via blockIdx.y)
// ---------------------------------------------------------------------------
__global__ __launch_bounds__(256) void cvt_bf16x3(
    const float* __restrict__ X0, const float* __restrict__ X1, const float* __restrict__ X2,
    unsigned short* __restrict__ O0, unsigned short* __restrict__ O1, unsigned short* __restrict__ O2)
{
  const int z = blockIdx.y;
  const float* X = z==0?X0 : z==1?X1 : X2;
  unsigned short* O = z==0?O0 : z==1?O1 : O2;
  const size_t i = ((size_t)blockIdx.x*256 + threadIdx.x)*8;
  const float4 a = *(const float4*)(X+i);
  const float4 b = *(const float4*)(X+i+4);
  union { unsigned u[4]; int4 v; } pk;
  pk.u[0] = cvtpk(a.x, a.y);
  pk.u[1] = cvtpk(a.z, a.w);
  pk.u[2] = cvtpk(b.x, b.y);
  pk.u[3] = cvtpk(b.z, b.w);
  *(int4*)(O+i) = pk.v;
}

// ---------------------------------------------------------------------------
// Pass 0: W [k][n] fp32  ->  Wt [n][k] bf16   (4 weights via blockIdx.z)
// ---------------------------------------------------------------------------
__global__ __launch_bounds__(256) void transpose_w(
    const float* __restrict__ W0, const float* __restrict__ W1,
    const float* __restrict__ W2, const float* __restrict__ W3,
    unsigned short* __restrict__ T0, unsigned short* __restrict__ T1,
    unsigned short* __restrict__ T2, unsigned short* __restrict__ T3)
{
  __shared__ float tile[32][33];
  const int z = blockIdx.z;
  const float* W = z==0?W0 : z==1?W1 : z==2?W2 : W3;
  unsigned short* T = z==0?T0 : z==1?T1 : z==2?T2 : T3;
  const int k0 = blockIdx.x*32, n0 = blockIdx.y*32;
  const int tx = threadIdx.x & 31, ty = threadIdx.x >> 5;   // 32 x 8
  #pragma unroll
  for (int i=0;i<4;i++) tile[ty+i*8][tx] = W[(size_t)(k0+ty+i*8)*Dq + n0+tx];
  __syncthreads();
  #pragma unroll
  for (int i=0;i<4;i++) T[(size_t)(n0+ty+i*8)*Dq + k0+tx] = f2bf(tile[tx][ty+i*8]);
}

// ---------------------------------------------------------------------------
// Pass 0b: V [b][s][h*64+d] bf16 -> V^T [bh][d][s] bf16 (once)
// ---------------------------------------------------------------------------
__global__ __launch_bounds__(256) void transpose_v(
    const unsigned short* __restrict__ Vb, unsigned short* __restrict__ Vo)
{
  __shared__ unsigned short t2[64][72];      // [d][s], pad 72
  const int bh = blockIdx.y;                 // 64 = b*16+h
  const int b = bh >> 4, h = bh & 15;
  const int s0 = blockIdx.x * 64;
  const int tid = threadIdx.x;
  const int r = tid >> 3, c8 = tid & 7;      // 32 rows x 8 chunks
  #pragma unroll
  for (int i=0;i<2;i++){
    int s = r + i*32;
    union { int4 v; unsigned short u[8]; } uu;
    uu.v = *(const int4*)(Vb + ((size_t)b*Sq + s0 + s)*Dq + h*HDq + c8*8);
    #pragma unroll
    for (int jj=0;jj<8;jj++){
      int j = (jj + c8) & 7;                 // rotate -> 2 lanes/bank (free)
      t2[c8*8 + j][s] = uu.u[j];
    }
  }
  __syncthreads();
  #pragma unroll
  for (int i=0;i<2;i++){
    int d = r + i*32;
    *(int4*)(Vo + ((size_t)bh*HDq + d)*Sq + s0 + c8*8) = *(const int4*)&t2[d][c8*8];
  }
}

// ---------------------------------------------------------------------------
// GEMM mainloop (R10 config — best measured): 128x128 tile, BK=32, 3 LDS
// buffers (48KB), stage tile t+2 while computing t, s_waitcnt vmcnt(4),
// ONE barrier per K-step. Swizzle chunk' = chunk ^ ((row>>1)&3) (conflict-free,
// verified: SQ_LDS_BANK_CONFLICT = 0).
// ---------------------------------------------------------------------------
__device__ __forceinline__ void gemm_loop(const unsigned short* __restrict__ A,
    const unsigned short* __restrict__ Bt,
    int bm, int bn, unsigned short* Al, unsigned short* Bl, f32x4 acc[4][4])
{
  const int tid = threadIdx.x;
  const int lane = tid & 63, wid = tid >> 6;
  const int lr = lane & 15, lg = lane >> 4;
  const int wm = wid >> 1, wn = wid & 1;

  #define STG(buf, k0) { \
    unsigned short* Ad = Al + (buf)*4096 + wid*512; \
    unsigned short* Bd = Bl + (buf)*4096 + wid*512; \
    _Pragma("unroll") \
    for (int i=0;i<2;i++){ \
      const int row = i*64 + (tid>>2); \
      const int cl  = (tid&3) ^ ((row>>1)&3); \
      gload16(A  + (size_t)(bm*128+row)*Dq + (k0) + cl*8, Ad + i*2048); \
      gload16(Bt + (size_t)(bn*128+row)*Dq + (k0) + cl*8, Bd + i*2048); \
    } }

  STG(0, 0);
  STG(1, 32);
  asm volatile("s_waitcnt vmcnt(4)" ::: "memory");   // tile 0 landed
  __syncthreads();

  const int cr = (lg ^ ((lr >> 1) & 3)) * 8;         // swizzled read chunk
  for (int t = 0; t < 32; ++t){
    const int buf = t % 3;
    const unsigned short* Ab = Al + buf*4096;
    const unsigned short* Bb = Bl + buf*4096;
    bf16x8 af[4], bfv[4];
    #pragma unroll
    for (int mt=0;mt<4;mt++) af[mt]  = *(const bf16x8*)(Ab + (wm*64+mt*16+lr)*32 + cr);
    #pragma unroll
    for (int nt=0;nt<4;nt++) bfv[nt] = *(const bf16x8*)(Bb + (wn*64+nt*16+lr)*32 + cr);

    if (t + 2 < 32) {
      STG((t+2)%3, (t+2)*32);                        // buf was last read at t-1
      asm volatile("s_waitcnt vmcnt(4)" ::: "memory"); // tile t+1 landed
    } else if (t == 30) {
      asm volatile("s_waitcnt vmcnt(0)" ::: "memory"); // tail: tile 31 landed
    }

    #pragma unroll
    for (int mt=0;mt<4;mt++)
      #pragma unroll
      for (int nt=0;nt<4;nt++)
        acc[mt][nt] = MFMA(af[mt], bfv[nt], acc[mt][nt]);

    __syncthreads();                                 // readers of buf done
  }
  #undef STG
}

// ---------------------------------------------------------------------------
// Pass 1: q/k/v = bf16( (Xbf @ W + b + lev) * scl )
// ---------------------------------------------------------------------------
__global__ __launch_bounds__(256, 3) void proj_gemm(
    const unsigned short* __restrict__ Aq, const unsigned short* __restrict__ Ak, const unsigned short* __restrict__ Av,
    const float* __restrict__ Lq, const float* __restrict__ Lk, const float* __restrict__ Lv,
    const unsigned short* __restrict__ Tq, const unsigned short* __restrict__ Tk, const unsigned short* __restrict__ Tv,
    const float* __restrict__ bqp, const float* __restrict__ bkp, const float* __restrict__ bvp,
    unsigned short* __restrict__ Oq, unsigned short* __restrict__ Ok, unsigned short* __restrict__ Ov)
{
  __shared__ __align__(16) unsigned short Al[3*4096];
  __shared__ __align__(16) unsigned short Bl[3*4096];

  const int bid = blockIdx.x;                     // 0..1535, 1536 % 8 == 0
  const int swz = (bid & 7)*192 + (bid >> 3);     // XCD-contiguous, bijective
  const int z   = swz >> 9;
  const int rem = swz & 511;
  const int bm  = rem >> 3, bn = rem & 7;

  const unsigned short* A = z==0?Aq : z==1?Ak : Av;
  const float* Lev = z==0?Lq : z==1?Lk : Lv;
  const unsigned short* Bt = z==0?Tq : z==1?Tk : Tv;
  const float* bias = z==0?bqp : z==1?bkp : bvp;
  unsigned short* Out = z==0?Oq : z==1?Ok : Ov;
  const float scl = (z==0) ? SC_Q : 1.0f;

  f32x4 acc[4][4];
  #pragma unroll
  for (int mt=0;mt<4;mt++)
    #pragma unroll
    for (int nt=0;nt<4;nt++) acc[mt][nt] = (f32x4){0.f,0.f,0.f,0.f};

  gemm_loop(A, Bt, bm, bn, Al, Bl, acc);

  const int tid = threadIdx.x, lane = tid&63, wid = tid>>6;
  const int lr = lane&15, lg = lane>>4, wm = wid>>1, wn = wid&1;
  const int colb = bn*128 + wn*64;
  float bcol[4];
  #pragma unroll
  for (int nt=0;nt<4;nt++) bcol[nt] = bias[colb + nt*16 + lr];
  #pragma unroll
  for (int mt=0;mt<4;mt++){
    int g = bm*128 + wm*64 + mt*16 + lg*4;
    #pragma unroll
    for (int r=0;r<4;r++){
      size_t ro = (size_t)(g+r)*Dq;
      #pragma unroll
      for (int nt=0;nt<4;nt++){
        int col = colb + nt*16 + lr;
        float v = (acc[mt][nt][r] + bcol[nt] + Lev[ro + col]) * scl;
        Out[ro + col] = f2bf(v);
      }
    }
  }
}

// ---------------------------------------------------------------------------
// Pass 2: flash attention, swapped-QK^T 32x32, QK-one-tile-ahead pipeline.
// R13 failed because __launch_bounds__(512,4) capped VGPR at 64 -> pipeline
// state spilled to scratch (WRITE_SIZE 16->39MB). Fix: (512,2) -> 128 VGPR.
// ---------------------------------------------------------------------------
__device__ __forceinline__ float comb_max(float x){ return fmaxf(x, __shfl_xor(x, 32, 64)); }
__device__ __forceinline__ float comb_sum(float x){ return x + __shfl_xor(x, 32, 64); }
__device__ __forceinline__ float max3(float a, float b, float c){ return fmaxf(fmaxf(a,b),c); }

// pack 16 f32 P-values into two PV A-frags; 4 shfl (pre-selected payload)
__device__ __forceinline__ void pack_p(const f32x16& t, int hi, bf16x8& c0, bf16x8& c1){
  unsigned w[8];
  #pragma unroll
  for (int j=0;j<8;j++) w[j] = cvtpk(t[2*j], t[2*j+1]);
  unsigned z0 = hi ? w[0] : w[2];
  unsigned z1 = hi ? w[1] : w[3];
  unsigned z2 = hi ? w[4] : w[6];
  unsigned z3 = hi ? w[5] : w[7];
  unsigned x0 = (unsigned)__shfl_xor((int)z0, 32, 64);
  unsigned x1 = (unsigned)__shfl_xor((int)z1, 32, 64);
  unsigned x2 = (unsigned)__shfl_xor((int)z2, 32, 64);
  unsigned x3 = (unsigned)__shfl_xor((int)z3, 32, 64);
  union { unsigned u[4]; bf16x8 v; } p0, p1;
  p0.u[0] = hi ? x0   : w[0];
  p0.u[1] = hi ? x1   : w[1];
  p0.u[2] = hi ? w[2] : x0;
  p0.u[3] = hi ? w[3] : x1;
  p1.u[0] = hi ? x2   : w[4];
  p1.u[1] = hi ? x3   : w[5];
  p1.u[2] = hi ? w[6] : x2;
  p1.u[3] = hi ? w[7] : x3;
  c0 = p0.v; c1 = p1.v;
}

__global__ __launch_bounds__(512, 2) void attn_k(
    const unsigned short* qb, const unsigned short* __restrict__ kb,
    const unsigned short* __restrict__ vt, unsigned short* cb)
{
  __shared__ unsigned short Kl[2][64*64];   // [key][d-chunk swizzled]
  __shared__ unsigned short Vl[2][64*64];   // [d][key-chunk swizzled]
  __shared__ float Rl[8][32];               // per-wave q-indexed broadcast

  const int bid = blockIdx.x;
  const int swz = (bid & 7)*64 + (bid >> 3);     // 512 % 8 == 0: bijective
  const int qt = swz & 7, bh = swz >> 3;         // 8 q-tiles x 64 heads
  const int b = bh >> 4, h = bh & 15;
  const size_t base = (size_t)b*Sq*Dq + (size_t)h*HDq;

  const int tid = threadIdx.x, lane = tid & 63, wid = tid >> 6;  // 8 waves
  const int ln31 = lane & 31, hi = lane >> 5;
  const int q0 = qt*256 + wid*32;

  bf16x8 qf[4];
  {
    const unsigned short* qp = qb + base + (size_t)(q0 + ln31)*Dq + hi*8;
    #pragma unroll
    for (int dk=0;dk<4;dk++) qf[dk] = *(const bf16x8*)(qp + dk*16);
  }

  const int kRow = tid >> 3, kCh = tid & 7;
  const unsigned short* kSrc = kb + base + (size_t)kRow*Dq + kCh*8;
  const unsigned short* vSrc = vt + ((size_t)bh*HDq + kRow)*Sq + kCh*8;
  const int wOff = kRow*64 + ((kCh ^ (kRow & 7))*8);

  // ---- prologue: stage K(0), V(0), K(1) ----
  {
    int4 k0r = *(const int4*)kSrc;
    int4 v0r = *(const int4*)vSrc;
    int4 k1r = *(const int4*)(kSrc + (size_t)64*Dq);
    *(int4*)&Kl[0][wOff] = k0r;
    *(int4*)&Vl[0][wOff] = v0r;
    *(int4*)&Kl[1][wOff] = k1r;
  }

  f32x16 o0 = (f32x16)(0.0f), o1 = (f32x16)(0.0f);
  float m = -1e30f, l = 0.f;

  __syncthreads();                               // prologue staging visible

  // ---- S(0) from Kl[0] ----
  f32x16 c0 = (f32x16)(0.0f), c1 = (f32x16)(0.0f);
  #pragma unroll
  for (int dk=0;dk<4;dk++){
    const int c = hi + dk*2;
    bf16x8 kf0 = *(const bf16x8*)&Kl[0][(ln31)*64    + ((c ^ (ln31 & 7))*8)];
    bf16x8 kf1 = *(const bf16x8*)&Kl[0][(32+ln31)*64 + ((c ^ (ln31 & 7))*8)];
    c0 = MFMA32(kf0, qf[dk], c0);
    c1 = MFMA32(kf1, qf[dk], c1);
  }

  int4 kreg = {0,0,0,0}, vreg = {0,0,0,0};

  for (int kt = 0; kt < Sq/64; ++kt){
    __syncthreads();                             // prev iter's staging visible;
                                                 // all waves past their reads
    const int pn = (kt+1) & 1;                   // K(t+1) buffer
    if (kt+2 < Sq/64) kreg = *(const int4*)(kSrc + (size_t)(kt+2)*64*Dq);
    if (kt+1 < Sq/64) vreg = *(const int4*)(vSrc + (kt+1)*64);

    // ---- QK-low(t+1): keys 0..31 of next tile (overlaps softmax below) ----
    f32x16 n0 = (f32x16)(0.0f);
    if (kt+1 < Sq/64){
      #pragma unroll
      for (int dk=0;dk<4;dk++){
        const int c = hi + dk*2;
        bf16x8 kf0 = *(const bf16x8*)&Kl[pn][(ln31)*64 + ((c ^ (ln31 & 7))*8)];
        n0 = MFMA32(kf0, qf[dk], n0);
      }
    }

    // ---- softmax on c0,c1 (S(t)) ----
    float u0 = max3(max3(c0[0], c0[1],  c0[2]),  max3(c0[3],  c0[4],  c0[5]),
                    max3(c0[6], c0[7],  c0[8]));
    float u1 = max3(max3(c0[9], c0[10], c0[11]), max3(c0[12], c0[13], c0[14]),
                    c0[15]);
    float u2 = max3(max3(c1[0], c1[1],  c1[2]),  max3(c1[3],  c1[4],  c1[5]),
                    max3(c1[6], c1[7],  c1[8]));
    float u3 = max3(max3(c1[9], c1[10], c1[11]), max3(c1[12], c1[13], c1[14]),
                    c1[15]);
    float tmax = comb_max(max3(max3(u0, u1, u2), u3, -1e30f));

    if (__any(tmax > m + 8.0f)){
      float mn = fmaxf(m, tmax);
      float al = __builtin_amdgcn_exp2f(m - mn);
      m = mn;
      l *= al;
      if (hi == 0) Rl[wid][ln31] = al;
      asm volatile("" ::: "memory");
      f32x4 av[4];
      #pragma unroll
      for (int g=0; g<4; g++) av[g] = *(const f32x4*)&Rl[wid][g*8 + hi*4];
      #pragma unroll
      for (int r=0;r<16;r++){ o0[r] *= av[r>>2][r&3]; o1[r] *= av[r>>2][r&3]; }
    }

    float s0 = 0.f, s1 = 0.f, s2 = 0.f, s3 = 0.f;
    #pragma unroll
    for (int r=0;r<16;r+=4){
      float a0 = __builtin_amdgcn_exp2f(c0[r]   - m); c0[r]   = a0; s0 += a0;
      float a1 = __builtin_amdgcn_exp2f(c0[r+1] - m); c0[r+1] = a1; s1 += a1;
      float a2 = __builtin_amdgcn_exp2f(c0[r+2] - m); c0[r+2] = a2; s2 += a2;
      float a3 = __builtin_amdgcn_exp2f(c0[r+3] - m); c0[r+3] = a3; s3 += a3;
    }
    #pragma unroll
    for (int r=0;r<16;r+=4){
      float a0 = __builtin_amdgcn_exp2f(c1[r]   - m); c1[r]   = a0; s0 += a0;
      float a1 = __builtin_amdgcn_exp2f(c1[r+1] - m); c1[r+1] = a1; s1 += a1;
      float a2 = __builtin_amdgcn_exp2f(c1[r+2] - m); c1[r+2] = a2; s2 += a2;
      float a3 = __builtin_amdgcn_exp2f(c1[r+3] - m); c1[r+3] = a3; s3 += a3;
    }
    l += comb_sum((s0 + s1) + (s2 + s3));

    // ---- pack + PV(t) from Vl[t&1] ----
    {
      const int p = kt & 1;
      bf16x8 pa0, pa1, pa2, pa3;
      pack_p(c0, hi, pa0, pa1);
      pack_p(c1, hi, pa2, pa3);
      #pragma unroll
      for (int c=0;c<4;c++){
        bf16x8 pa = c==0?pa0 : c==1?pa1 : c==2?pa2 : pa3;
        const int vc = 2*c + hi;
        bf16x8 vf0 = *(const bf16x8*)&Vl[p][(ln31)*64    + ((vc ^ (ln31 & 7))*8)];
        bf16x8 vf1 = *(const bf16x8*)&Vl[p][(32+ln31)*64 + ((vc ^ (ln31 & 7))*8)];
        o0 = MFMA32(pa, vf0, o0);
        o1 = MFMA32(pa, vf1, o1);
      }
    }

    // ---- QK-high(t+1): keys 32..63 of next tile ----
    f32x16 n1 = (f32x16)(0.0f);
    if (kt+1 < Sq/64){
      #pragma unroll
      for (int dk=0;dk<4;dk++){
        const int c = hi + dk*2;
        bf16x8 kf1 = *(const bf16x8*)&Kl[pn][(32+ln31)*64 + ((c ^ (ln31 & 7))*8)];
        n1 = MFMA32(kf1, qf[dk], n1);
      }
    }

    // ---- stage K(t+2) -> Kl[t&1], V(t+1) -> Vl[(t+1)&1] ----
    // Safe pre-barrier: no concurrent reader touches these bufs this iter
    // (QK reads Kl[(t+1)&1], PV reads Vl[t&1]).
    if (kt+2 < Sq/64) *(int4*)&Kl[kt & 1][wOff] = kreg;
    if (kt+1 < Sq/64) *(int4*)&Vl[pn][wOff]     = vreg;

    c0 = n0; c1 = n1;
  }

  // ---- epilogue: O / l, write ctx ----
  float linv = __builtin_amdgcn_rcpf(l);
  if (hi == 0) Rl[wid][ln31] = linv;
  asm volatile("" ::: "memory");
  f32x4 lv[4];
  #pragma unroll
  for (int g=0; g<4; g++) lv[g] = *(const f32x4*)&Rl[wid][g*8 + hi*4];
  #pragma unroll
  for (int r=0;r<16;r++){
    int q = (r&3) + 8*(r>>2) + 4*hi;
    size_t ro = base + (size_t)(q0 + q)*Dq;
    cb[ro + ln31]      = f2bf(o0[r] * lv[r>>2][r&3]);
    cb[ro + 32 + ln31] = f2bf(o1[r] * lv[r>>2][r&3]);
  }
}

// ---------------------------------------------------------------------------
// Pass 3: out = ctx @ Wo + bo   (fp32 out); 1D grid 512 + XCD swizzle
// ---------------------------------------------------------------------------
__global__ __launch_bounds__(256, 3) void out_gemm(
    const unsigned short* __restrict__ Ctx, const unsigned short* __restrict__ To,
    const float* __restrict__ bop, float* __restrict__ Out)
{
  __shared__ __align__(16) unsigned short Al[3*4096];
  __shared__ __align__(16) unsigned short Bl[3*4096];

  const int bid = blockIdx.x;                    // 0..511
  const int swz = (bid & 7)*64 + (bid >> 3);     // XCD-contiguous, bijective
  const int bm  = swz >> 3, bn = swz & 7;

  f32x4 acc[4][4];
  #pragma unroll
  for (int mt=0;mt<4;mt++)
    #pragma unroll
    for (int nt=0;nt<4;nt++) acc[mt][nt] = (f32x4){0.f,0.f,0.f,0.f};

  gemm_loop(Ctx, To, bm, bn, Al, Bl, acc);

  const int tid = threadIdx.x, lane = tid&63, wid = tid>>6;
  const int lr = lane&15, lg = lane>>4, wm = wid>>1, wn = wid&1;
  const int colb = bn*128 + wn*64;
  float bcol[4];
  #pragma unroll
  for (int nt=0;nt<4;nt++) bcol[nt] = bop[colb + nt*16 + lr];
  #pragma unroll
  for (int mt=0;mt<4;mt++){
    int g = bm*128 + wm*64 + mt*16 + lg*4;
    #pragma unroll
    for (int r=0;r<4;r++){
      size_t ro = (size_t)(g+r)*Dq;
      #pragma unroll
      for (int nt=0;nt<4;nt++){
        int col = colb + nt*16 + lr;
        Out[ro + col] = acc[mt][nt][r] + bcol[nt];
      }
    }
  }
}

// ---------------------------------------------------------------------------
extern "C" void kernel_launch(void* const* d_in, const int* in_sizes, int n_in,
                              void* d_out, int out_size, void* d_ws, size_t ws_size,
                              hipStream_t stream) {
  const float* Q    = (const float*)d_in[0];
  const float* Qlev = (const float*)d_in[1];
  const float* K    = (const float*)d_in[2];
  const float* Klev = (const float*)d_in[3];
  const float* V    = (const float*)d_in[4];
  const float* Vlev = (const float*)d_in[5];
  const float* Wq   = (const float*)d_in[6];
  const float* bq   = (const float*)d_in[7];
  const float* Wk   = (const float*)d_in[8];
  const float* bk   = (const float*)d_in[9];
  const float* Wv   = (const float*)d_in[10];
  const float* bv   = (const float*)d_in[11];
  const float* Wo   = (const float*)d_in[12];
  const float* bo   = (const float*)d_in[13];

  unsigned short* qbuf = (unsigned short*)d_ws;
  unsigned short* kbuf = qbuf + (size_t)MR*Dq;
  unsigned short* vbuf = kbuf + (size_t)MR*Dq;
  unsigned short* xq   = vbuf + (size_t)MR*Dq;   // bf16(Q); later aliased as V^T
  unsigned short* xk   = xq   + (size_t)MR*Dq;
  unsigned short* xv   = xk   + (size_t)MR*Dq;
  unsigned short* Tq   = xv   + (size_t)MR*Dq;
  unsigned short* Tk   = Tq + (size_t)Dq*Dq;
  unsigned short* Tv   = Tk + (size_t)Dq*Dq;
  unsigned short* To   = Tv + (size_t)Dq*Dq;
  unsigned short* vtb  = xq;                     // alias: xq dead after proj_gemm

  cvt_bf16x3<<<dim3(MR*Dq/(256*8), 3), 256, 0, stream>>>(Q, K, V, xq, xk, xv);
  transpose_w<<<dim3(Dq/32, Dq/32, 4), 256, 0, stream>>>(Wq,Wk,Wv,Wo, Tq,Tk,Tv,To);
  proj_gemm<<<dim3(1536), 256, 0, stream>>>(
      xq,xk,xv, Qlev,Klev,Vlev, Tq,Tk,Tv, bq,bk,bv, qbuf,kbuf,vbuf);
  transpose_v<<<dim3(Sq/64, Bq*Hq), 256, 0, stream>>>(vbuf, vtb);
  attn_k<<<dim3(512), 512, 0, stream>>>(qbuf, kbuf, vtb, qbuf);
  out_gemm<<<dim3(512), 256, 0, stream>>>(qbuf, To, bo, (float*)d_out);
}

// Round 15
// 245.534 us; speedup vs baseline: 1.2569x; 1.0249x over previous
//
#include <hip/hip_runtime.h>
#include <hip/hip_bf16.h>

#define Bq 4
#define Sq 2048
#define Dq 1024
#define Hq 16
#define HDq 64
#define MR (Bq*Sq)   // 8192 rows

typedef __attribute__((ext_vector_type(8))) short bf16x8;
typedef __attribute__((ext_vector_type(4))) float f32x4;
typedef __attribute__((ext_vector_type(16))) float f32x16;

__device__ __forceinline__ unsigned short f2bf(float f){
  unsigned int x = __builtin_bit_cast(unsigned int, f);
  x += 0x7fffu + ((x >> 16) & 1u);          // round-to-nearest-even
  return (unsigned short)(x >> 16);
}

// HW packed f32x2 -> bf16x2 (RTNE)
__device__ __forceinline__ unsigned cvtpk(float a, float b){
  unsigned r;
  asm("v_cvt_pk_bf16_f32 %0, %1, %2" : "=v"(r) : "v"(a), "v"(b));
  return r;
}

#define MFMA(a,b,c)   __builtin_amdgcn_mfma_f32_16x16x32_bf16((a),(b),(c),0,0,0)
#define MFMA32(a,b,c) __builtin_amdgcn_mfma_f32_32x32x16_bf16((a),(b),(c),0,0,0)

#define SC_Q 0.18033688f   // 0.125 * log2(e), folded into q projection

// async global->LDS, 16B per lane; LDS dest = wave-uniform base + lane*16
__device__ __forceinline__ void gload16(const unsigned short* g, unsigned short* l){
  __builtin_amdgcn_global_load_lds(
      (const __attribute__((address_space(1))) void*)g,
      (__attribute__((address_space(3))) void*)l, 16, 0, 0);
}

// ---------------------------------------------------------------------------
// Pass -1: X fp32 -> bf16 (Q,K,V via blockIdx.y)
// ---------------------------------------------------------------------------
__global__ __launch_bounds__(256) void cvt_bf16x3(
    const float* __restrict__ X0, const float* __restrict__ X1, const float* __restrict__ X2,
    unsigned short* __restrict__ O0, unsigned short* __restrict__ O1, unsigned short* __restrict__ O2)
{
  const int z = blockIdx.y;
  const float* X = z==0?X0 : z==1?X1 : X2;
  unsigned short* O = z==0?O0 : z==1?O1 : O2;
  const size_t i = ((size_t)blockIdx.x*256 + threadIdx.x)*8;
  const float4 a = *(const float4*)(X+i);
  const float4 b = *(const float4*)(X+i+4);
  union { unsigned u[4]; int4 v; } pk;
  pk.u[0] = cvtpk(a.x, a.y);
  pk.u[1] = cvtpk(a.z, a.w);
  pk.u[2] = cvtpk(b.x, b.y);
  pk.u[3] = cvtpk(b.z, b.w);
  *(int4*)(O+i) = pk.v;
}

// ---------------------------------------------------------------------------
// Pass 0: W [k][n] fp32  ->  Wt [n][k] bf16   (4 weights via blockIdx.z)
// ---------------------------------------------------------------------------
__global__ __launch_bounds__(256) void transpose_w(
    const float* __restrict__ W0, const float* __restrict__ W1,
    const float* __restrict__ W2, const float* __restrict__ W3,
    unsigned short* __restrict__ T0, unsigned short* __restrict__ T1,
    unsigned short* __restrict__ T2, unsigned short* __restrict__ T3)
{
  __shared__ float tile[32][33];
  const int z = blockIdx.z;
  const float* W = z==0?W0 : z==1?W1 : z==2?W2 : W3;
  unsigned short* T = z==0?T0 : z==1?T1 : z==2?T2 : T3;
  const int k0 = blockIdx.x*32, n0 = blockIdx.y*32;
  const int tx = threadIdx.x & 31, ty = threadIdx.x >> 5;   // 32 x 8
  #pragma unroll
  for (int i=0;i<4;i++) tile[ty+i*8][tx] = W[(size_t)(k0+ty+i*8)*Dq + n0+tx];
  __syncthreads();
  #pragma unroll
  for (int i=0;i<4;i++) T[(size_t)(n0+ty+i*8)*Dq + k0+tx] = f2bf(tile[tx][ty+i*8]);
}

// ---------------------------------------------------------------------------
// Pass 0b: V [b][s][h*64+d] bf16 -> V^T [bh][d][s] bf16 (once)
// ---------------------------------------------------------------------------
__global__ __launch_bounds__(256) void transpose_v(
    const unsigned short* __restrict__ Vb, unsigned short* __restrict__ Vo)
{
  __shared__ unsigned short t2[64][72];      // [d][s], pad 72
  const int bh = blockIdx.y;                 // 64 = b*16+h
  const int b = bh >> 4, h = bh & 15;
  const int s0 = blockIdx.x * 64;
  const int tid = threadIdx.x;
  const int r = tid >> 3, c8 = tid & 7;      // 32 rows x 8 chunks
  #pragma unroll
  for (int i=0;i<2;i++){
    int s = r + i*32;
    union { int4 v; unsigned short u[8]; } uu;
    uu.v = *(const int4*)(Vb + ((size_t)b*Sq + s0 + s)*Dq + h*HDq + c8*8);
    #pragma unroll
    for (int jj=0;jj<8;jj++){
      int j = (jj + c8) & 7;                 // rotate -> 2 lanes/bank (free)
      t2[c8*8 + j][s] = uu.u[j];
    }
  }
  __syncthreads();
  #pragma unroll
  for (int i=0;i<2;i++){
    int d = r + i*32;
    *(int4*)(Vo + ((size_t)bh*HDq + d)*Sq + s0 + c8*8) = *(const int4*)&t2[d][c8*8];
  }
}

// ---------------------------------------------------------------------------
// GEMM mainloop: R10 config (128x128 tile, BK=32, 3 LDS bufs, stage-2-ahead,
// counted vmcnt(4)) with RAW s_barrier instead of __syncthreads.
// __syncthreads emits s_waitcnt vmcnt(0) before s_barrier, draining the
// global_load_lds queue every K-step and defeating the counted pipeline (the
// documented m97-ceiling mechanism). Raw barrier is safe here: each wave's
// vmcnt(4) retires ITS tile t+1 loads pre-barrier; buf-t reads are consumed
// by MFMAs (compiler lgkmcnt) pre-barrier; overwrites of buf t are issued
// post-barrier two iters later. No ds_writes in this loop.
// ---------------------------------------------------------------------------
__device__ __forceinline__ void gemm_loop(const unsigned short* __restrict__ A,
    const unsigned short* __restrict__ Bt,
    int bm, int bn, unsigned short* Al, unsigned short* Bl, f32x4 acc[4][4])
{
  const int tid = threadIdx.x;
  const int lane = tid & 63, wid = tid >> 6;
  const int lr = lane & 15, lg = lane >> 4;
  const int wm = wid >> 1, wn = wid & 1;

  #define STG(buf, k0) { \
    unsigned short* Ad = Al + (buf)*4096 + wid*512; \
    unsigned short* Bd = Bl + (buf)*4096 + wid*512; \
    _Pragma("unroll") \
    for (int i=0;i<2;i++){ \
      const int row = i*64 + (tid>>2); \
      const int cl  = (tid&3) ^ ((row>>1)&3); \
      gload16(A  + (size_t)(bm*128+row)*Dq + (k0) + cl*8, Ad + i*2048); \
      gload16(Bt + (size_t)(bn*128+row)*Dq + (k0) + cl*8, Bd + i*2048); \
    } }

  STG(0, 0);
  STG(1, 32);
  asm volatile("s_waitcnt vmcnt(4)" ::: "memory");   // own tile-0 loads landed
  __builtin_amdgcn_s_barrier();                      // all waves' tile 0 in LDS
  asm volatile("" ::: "memory");

  const int cr = (lg ^ ((lr >> 1) & 3)) * 8;         // swizzled read chunk
  for (int t = 0; t < 32; ++t){
    const int buf = t % 3;
    const unsigned short* Ab = Al + buf*4096;
    const unsigned short* Bb = Bl + buf*4096;
    bf16x8 af[4], bfv[4];
    #pragma unroll
    for (int mt=0;mt<4;mt++) af[mt]  = *(const bf16x8*)(Ab + (wm*64+mt*16+lr)*32 + cr);
    #pragma unroll
    for (int nt=0;nt<4;nt++) bfv[nt] = *(const bf16x8*)(Bb + (wn*64+nt*16+lr)*32 + cr);

    if (t + 2 < 32) {
      STG((t+2)%3, (t+2)*32);                        // buf was last read at t-1
      asm volatile("s_waitcnt vmcnt(4)" ::: "memory"); // own tile t+1 retired
    } else if (t == 30) {
      asm volatile("s_waitcnt vmcnt(0)" ::: "memory"); // tail: tile 31 landed
    }

    #pragma unroll
    for (int mt=0;mt<4;mt++)
      #pragma unroll
      for (int nt=0;nt<4;nt++)
        acc[mt][nt] = MFMA(af[mt], bfv[nt], acc[mt][nt]);

    __builtin_amdgcn_s_barrier();                    // NO vmcnt drain
    asm volatile("" ::: "memory");
  }
  #undef STG
}

// ---------------------------------------------------------------------------
// Pass 1: q/k/v = bf16( (Xbf @ W + b + lev) * scl )
// ---------------------------------------------------------------------------
__global__ __launch_bounds__(256, 3) void proj_gemm(
    const unsigned short* __restrict__ Aq, const unsigned short* __restrict__ Ak, const unsigned short* __restrict__ Av,
    const float* __restrict__ Lq, const float* __restrict__ Lk, const float* __restrict__ Lv,
    const unsigned short* __restrict__ Tq, const unsigned short* __restrict__ Tk, const unsigned short* __restrict__ Tv,
    const float* __restrict__ bqp, const float* __restrict__ bkp, const float* __restrict__ bvp,
    unsigned short* __restrict__ Oq, unsigned short* __restrict__ Ok, unsigned short* __restrict__ Ov)
{
  __shared__ __align__(16) unsigned short Al[3*4096];
  __shared__ __align__(16) unsigned short Bl[3*4096];

  const int bid = blockIdx.x;                     // 0..1535, 1536 % 8 == 0
  const int swz = (bid & 7)*192 + (bid >> 3);     // XCD-contiguous, bijective
  const int z   = swz >> 9;
  const int rem = swz & 511;
  const int bm  = rem >> 3, bn = rem & 7;

  const unsigned short* A = z==0?Aq : z==1?Ak : Av;
  const float* Lev = z==0?Lq : z==1?Lk : Lv;
  const unsigned short* Bt = z==0?Tq : z==1?Tk : Tv;
  const float* bias = z==0?bqp : z==1?bkp : bvp;
  unsigned short* Out = z==0?Oq : z==1?Ok : Ov;
  const float scl = (z==0) ? SC_Q : 1.0f;

  f32x4 acc[4][4];
  #pragma unroll
  for (int mt=0;mt<4;mt++)
    #pragma unroll
    for (int nt=0;nt<4;nt++) acc[mt][nt] = (f32x4){0.f,0.f,0.f,0.f};

  gemm_loop(A, Bt, bm, bn, Al, Bl, acc);

  const int tid = threadIdx.x, lane = tid&63, wid = tid>>6;
  const int lr = lane&15, lg = lane>>4, wm = wid>>1, wn = wid&1;
  const int colb = bn*128 + wn*64;
  float bcol[4];
  #pragma unroll
  for (int nt=0;nt<4;nt++) bcol[nt] = bias[colb + nt*16 + lr];
  #pragma unroll
  for (int mt=0;mt<4;mt++){
    int g = bm*128 + wm*64 + mt*16 + lg*4;
    #pragma unroll
    for (int r=0;r<4;r++){
      size_t ro = (size_t)(g+r)*Dq;
      #pragma unroll
      for (int nt=0;nt<4;nt++){
        int col = colb + nt*16 + lr;
        float v = (acc[mt][nt][r] + bcol[nt] + Lev[ro + col]) * scl;
        Out[ro + col] = f2bf(v);
      }
    }
  }
}

// ---------------------------------------------------------------------------
// Pass 2: flash attention — R12 structure (best measured: 100.5us), with the
// correctness-verified 4-shfl pack_p. __syncthreads kept (ds_write staging
// needs the lgkmcnt drain).
// ---------------------------------------------------------------------------
__device__ __forceinline__ float comb_max(float x){ return fmaxf(x, __shfl_xor(x, 32, 64)); }
__device__ __forceinline__ float comb_sum(float x){ return x + __shfl_xor(x, 32, 64); }
__device__ __forceinline__ float max3(float a, float b, float c){ return fmaxf(fmaxf(a,b),c); }

// pack 16 f32 P-values into two PV A-frags; 4 shfl (pre-selected payload)
__device__ __forceinline__ void pack_p(const f32x16& t, int hi, bf16x8& c0, bf16x8& c1){
  unsigned w[8];
  #pragma unroll
  for (int j=0;j<8;j++) w[j] = cvtpk(t[2*j], t[2*j+1]);
  unsigned z0 = hi ? w[0] : w[2];
  unsigned z1 = hi ? w[1] : w[3];
  unsigned z2 = hi ? w[4] : w[6];
  unsigned z3 = hi ? w[5] : w[7];
  unsigned x0 = (unsigned)__shfl_xor((int)z0, 32, 64);
  unsigned x1 = (unsigned)__shfl_xor((int)z1, 32, 64);
  unsigned x2 = (unsigned)__shfl_xor((int)z2, 32, 64);
  unsigned x3 = (unsigned)__shfl_xor((int)z3, 32, 64);
  union { unsigned u[4]; bf16x8 v; } p0, p1;
  p0.u[0] = hi ? x0   : w[0];
  p0.u[1] = hi ? x1   : w[1];
  p0.u[2] = hi ? w[2] : x0;
  p0.u[3] = hi ? w[3] : x1;
  p1.u[0] = hi ? x2   : w[4];
  p1.u[1] = hi ? x3   : w[5];
  p1.u[2] = hi ? w[6] : x2;
  p1.u[3] = hi ? w[7] : x3;
  c0 = p0.v; c1 = p1.v;
}

__global__ __launch_bounds__(512, 4) void attn_k(
    const unsigned short* qb, const unsigned short* __restrict__ kb,
    const unsigned short* __restrict__ vt, unsigned short* cb)
{
  __shared__ unsigned short Kl[2][64*64];   // [key][d-chunk swizzled]
  __shared__ unsigned short Vl[2][64*64];   // [d][key-chunk swizzled]
  __shared__ float Rl[8][32];               // per-wave q-indexed broadcast

  const int bid = blockIdx.x;
  const int swz = (bid & 7)*64 + (bid >> 3);     // 512 % 8 == 0: bijective
  const int qt = swz & 7, bh = swz >> 3;         // 8 q-tiles x 64 heads
  const int b = bh >> 4, h = bh & 15;
  const size_t base = (size_t)b*Sq*Dq + (size_t)h*HDq;

  const int tid = threadIdx.x, lane = tid & 63, wid = tid >> 6;  // 8 waves
  const int ln31 = lane & 31, hi = lane >> 5;
  const int q0 = qt*256 + wid*32;

  bf16x8 qf[4];
  {
    const unsigned short* qp = qb + base + (size_t)(q0 + ln31)*Dq + hi*8;
    #pragma unroll
    for (int dk=0;dk<4;dk++) qf[dk] = *(const bf16x8*)(qp + dk*16);
  }

  const int kRow = tid >> 3, kCh = tid & 7;
  const unsigned short* kSrc = kb + base + (size_t)kRow*Dq + kCh*8;
  const unsigned short* vSrc = vt + ((size_t)bh*HDq + kRow)*Sq + kCh*8;
  const int wOff = kRow*64 + ((kCh ^ (kRow & 7))*8);

  int4 kreg = *(const int4*)kSrc;
  int4 vreg = *(const int4*)vSrc;
  *(int4*)&Kl[0][wOff] = kreg;
  *(int4*)&Vl[0][wOff] = vreg;

  f32x16 o0 = (f32x16)(0.0f), o1 = (f32x16)(0.0f);
  float m = -1e30f, l = 0.f;

  for (int kt = 0; kt < Sq/64; ++kt){
    __syncthreads();                             // buf[kt&1] ready
    const int p = kt & 1;
    if (kt+1 < Sq/64){                           // prefetch next tile into regs
      kreg = *(const int4*)(kSrc + (size_t)(kt+1)*64*Dq);
      vreg = *(const int4*)(vSrc + (kt+1)*64);
    }

    f32x16 t0 = (f32x16)(0.0f), t1 = (f32x16)(0.0f);
    __builtin_amdgcn_s_setprio(1);
    #pragma unroll
    for (int dk=0;dk<4;dk++){
      const int c = hi + dk*2;
      bf16x8 kf0 = *(const bf16x8*)&Kl[p][(ln31)*64    + ((c ^ (ln31 & 7))*8)];
      bf16x8 kf1 = *(const bf16x8*)&Kl[p][(32+ln31)*64 + ((c ^ (ln31 & 7))*8)];
      t0 = MFMA32(kf0, qf[dk], t0);
      t1 = MFMA32(kf1, qf[dk], t1);
    }
    __builtin_amdgcn_s_setprio(0);

    // ---- max over 32 values: max3-shaped balanced tree (v_max3_f32 fusion)
    float u0 = max3(max3(t0[0], t0[1],  t0[2]),  max3(t0[3],  t0[4],  t0[5]),
                    max3(t0[6], t0[7],  t0[8]));
    float u1 = max3(max3(t0[9], t0[10], t0[11]), max3(t0[12], t0[13], t0[14]),
                    t0[15]);
    float u2 = max3(max3(t1[0], t1[1],  t1[2]),  max3(t1[3],  t1[4],  t1[5]),
                    max3(t1[6], t1[7],  t1[8]));
    float u3 = max3(max3(t1[9], t1[10], t1[11]), max3(t1[12], t1[13], t1[14]),
                    t1[15]);
    float tmax = comb_max(max3(max3(u0, u1, u2), u3, -1e30f));

    if (__any(tmax > m + 8.0f)){
      float mn = fmaxf(m, tmax);
      float al = __builtin_amdgcn_exp2f(m - mn);
      m = mn;
      l *= al;
      if (hi == 0) Rl[wid][ln31] = al;
      asm volatile("" ::: "memory");
      f32x4 av[4];
      #pragma unroll
      for (int g=0; g<4; g++) av[g] = *(const f32x4*)&Rl[wid][g*8 + hi*4];
      #pragma unroll
      for (int r=0;r<16;r++){ o0[r] *= av[r>>2][r&3]; o1[r] *= av[r>>2][r&3]; }
    }

    // ---- exp2 + 4-way partial sums (dependency chain 32 -> 8+3)
    float s0 = 0.f, s1 = 0.f, s2 = 0.f, s3 = 0.f;
    #pragma unroll
    for (int r=0;r<16;r+=4){
      float a0 = __builtin_amdgcn_exp2f(t0[r]   - m); t0[r]   = a0; s0 += a0;
      float a1 = __builtin_amdgcn_exp2f(t0[r+1] - m); t0[r+1] = a1; s1 += a1;
      float a2 = __builtin_amdgcn_exp2f(t0[r+2] - m); t0[r+2] = a2; s2 += a2;
      float a3 = __builtin_amdgcn_exp2f(t0[r+3] - m); t0[r+3] = a3; s3 += a3;
    }
    #pragma unroll
    for (int r=0;r<16;r+=4){
      float a0 = __builtin_amdgcn_exp2f(t1[r]   - m); t1[r]   = a0; s0 += a0;
      float a1 = __builtin_amdgcn_exp2f(t1[r+1] - m); t1[r+1] = a1; s1 += a1;
      float a2 = __builtin_amdgcn_exp2f(t1[r+2] - m); t1[r+2] = a2; s2 += a2;
      float a3 = __builtin_amdgcn_exp2f(t1[r+3] - m); t1[r+3] = a3; s3 += a3;
    }
    l += comb_sum((s0 + s1) + (s2 + s3));

    bf16x8 pa0, pa1, pa2, pa3;
    pack_p(t0, hi, pa0, pa1);
    pack_p(t1, hi, pa2, pa3);
    __builtin_amdgcn_s_setprio(1);
    #pragma unroll
    for (int c=0;c<4;c++){
      bf16x8 pa = c==0?pa0 : c==1?pa1 : c==2?pa2 : pa3;
      const int vc = 2*c + hi;
      bf16x8 vf0 = *(const bf16x8*)&Vl[p][(ln31)*64    + ((vc ^ (ln31 & 7))*8)];
      bf16x8 vf1 = *(const bf16x8*)&Vl[p][(32+ln31)*64 + ((vc ^ (ln31 & 7))*8)];
      o0 = MFMA32(pa, vf0, o0);
      o1 = MFMA32(pa, vf1, o1);
    }
    __builtin_amdgcn_s_setprio(0);

    if (kt+1 < Sq/64){
      const int pn = p ^ 1;
      *(int4*)&Kl[pn][wOff] = kreg;
      *(int4*)&Vl[pn][wOff] = vreg;
    }
  }

  float linv = __builtin_amdgcn_rcpf(l);
  if (hi == 0) Rl[wid][ln31] = linv;
  asm volatile("" ::: "memory");
  f32x4 lv[4];
  #pragma unroll
  for (int g=0; g<4; g++) lv[g] = *(const f32x4*)&Rl[wid][g*8 + hi*4];
  #pragma unroll
  for (int r=0;r<16;r++){
    int q = (r&3) + 8*(r>>2) + 4*hi;
    size_t ro = base + (size_t)(q0 + q)*Dq;
    cb[ro + ln31]      = f2bf(o0[r] * lv[r>>2][r&3]);
    cb[ro + 32 + ln31] = f2bf(o1[r] * lv[r>>2][r&3]);
  }
}

// ---------------------------------------------------------------------------
// Pass 3: out = ctx @ Wo + bo   (fp32 out); 1D grid 512 + XCD swizzle
// ---------------------------------------------------------------------------
__global__ __launch_bounds__(256, 3) void out_gemm(
    const unsigned short* __restrict__ Ctx, const unsigned short* __restrict__ To,
    const float* __restrict__ bop, float* __restrict__ Out)
{
  __shared__ __align__(16) unsigned short Al[3*4096];
  __shared__ __align__(16) unsigned short Bl[3*4096];

  const int bid = blockIdx.x;                    // 0..511
  const int swz = (bid & 7)*64 + (bid >> 3);     // XCD-contiguous, bijective
  const int bm  = swz >> 3, bn = swz & 7;

  f32x4 acc[4][4];
  #pragma unroll
  for (int mt=0;mt<4;mt++)
    #pragma unroll
    for (int nt=0;nt<4;nt++) acc[mt][nt] = (f32x4){0.f,0.f,0.f,0.f};

  gemm_loop(Ctx, To, bm, bn, Al, Bl, acc);

  const int tid = threadIdx.x, lane = tid&63, wid = tid>>6;
  const int lr = lane&15, lg = lane>>4, wm = wid>>1, wn = wid&1;
  const int colb = bn*128 + wn*64;
  float bcol[4];
  #pragma unroll
  for (int nt=0;nt<4;nt++) bcol[nt] = bop[colb + nt*16 + lr];
  #pragma unroll
  for (int mt=0;mt<4;mt++){
    int g = bm*128 + wm*64 + mt*16 + lg*4;
    #pragma unroll
    for (int r=0;r<4;r++){
      size_t ro = (size_t)(g+r)*Dq;
      #pragma unroll
      for (int nt=0;nt<4;nt++){
        int col = colb + nt*16 + lr;
        Out[ro + col] = acc[mt][nt][r] + bcol[nt];
      }
    }
  }
}

// ---------------------------------------------------------------------------
extern "C" void kernel_launch(void* const* d_in, const int* in_sizes, int n_in,
                              void* d_out, int out_size, void* d_ws, size_t ws_size,
                              hipStream_t stream) {
  const float* Q    = (const float*)d_in[0];
  const float* Qlev = (const float*)d_in[1];
  const float* K    = (const float*)d_in[2];
  const float* Klev = (const float*)d_in[3];
  const float* V    = (const float*)d_in[4];
  const float* Vlev = (const float*)d_in[5];
  const float* Wq   = (const float*)d_in[6];
  const float* bq   = (const float*)d_in[7];
  const float* Wk   = (const float*)d_in[8];
  const float* bk   = (const float*)d_in[9];
  const float* Wv   = (const float*)d_in[10];
  const float* bv   = (const float*)d_in[11];
  const float* Wo   = (const float*)d_in[12];
  const float* bo   = (const float*)d_in[13];

  unsigned short* qbuf = (unsigned short*)d_ws;
  unsigned short* kbuf = qbuf + (size_t)MR*Dq;
  unsigned short* vbuf = kbuf + (size_t)MR*Dq;
  unsigned short* xq   = vbuf + (size_t)MR*Dq;   // bf16(Q); later aliased as V^T
  unsigned short* xk   = xq   + (size_t)MR*Dq;
  unsigned short* xv   = xk   + (size_t)MR*Dq;
  unsigned short* Tq   = xv   + (size_t)MR*Dq;
  unsigned short* Tk   = Tq + (size_t)Dq*Dq;
  unsigned short* Tv   = Tk + (size_t)Dq*Dq;
  unsigned short* To   = Tv + (size_t)Dq*Dq;
  unsigned short* vtb  = xq;                     // alias: xq dead after proj_gemm

  cvt_bf16x3<<<dim3(MR*Dq/(256*8), 3), 256, 0, stream>>>(Q, K, V, xq, xk, xv);
  transpose_w<<<dim3(Dq/32, Dq/32, 4), 256, 0, stream>>>(Wq,Wk,Wv,Wo, Tq,Tk,Tv,To);
  proj_gemm<<<dim3(1536), 256, 0, stream>>>(
      xq,xk,xv, Qlev,Klev,Vlev, Tq,Tk,Tv, bq,bk,bv, qbuf,kbuf,vbuf);
  transpose_v<<<dim3(Sq/64, Bq*Hq), 256, 0, stream>>>(vbuf, vtb);
  attn_k<<<dim3(512), 512, 0, stream>>>(qbuf, kbuf, vtb, qbuf);
  out_gemm<<<dim3(512), 256, 0, stream>>>(qbuf, To, bo, (float*)d_out);
}